// Round 1
// baseline (391.413 us; speedup 1.0000x reference)
//
#include <hip/hip_runtime.h>
#include <hip/hip_bf16.h>

#define BB 2
#define SS 2048
#define DD 1024
#define HH 16
#define RR 64
#define DH 64
#define BH (BB*HH)      // 32
#define MM (BB*SS)      // 4096
#define CH 32
#define NCH (SS/CH)     // 64
#define CSROW (RR*DH + RR)  // 4160

using short8 = __attribute__((ext_vector_type(8))) short;
using f32x4  = __attribute__((ext_vector_type(4))) float;

// ---------------- convert q/k/v to bf16 (+ gather biases) ----------------
__global__ __launch_bounds__(256) void k_prep(
    const float* __restrict__ q, const float* __restrict__ k, const float* __restrict__ v,
    const float* __restrict__ bq, const float* __restrict__ bk, const float* __restrict__ bv,
    __hip_bfloat16* __restrict__ Xb, float* __restrict__ biasb)
{
    int z = blockIdx.y;
    const float* src = (z == 0) ? q : (z == 1) ? k : v;
    size_t i = ((size_t)blockIdx.x * 256 + threadIdx.x) * 4;
    float4 f = *(const float4*)(src + i);
    __hip_bfloat16* dst = Xb + (size_t)z * 4194304 + i;
    dst[0] = __float2bfloat16(f.x);
    dst[1] = __float2bfloat16(f.y);
    dst[2] = __float2bfloat16(f.z);
    dst[3] = __float2bfloat16(f.w);
    if (blockIdx.x == 0 && threadIdx.x < 1024) {
        const float* bb = (z == 0) ? bq : (z == 1) ? bk : bv;
        biasb[z * 1024 + threadIdx.x] = bb[threadIdx.x];
    }
}

// ---------------- transpose + convert weights: WT[n][k] = bf16(W[k][n]) ----------------
__global__ __launch_bounds__(256) void k_wt(
    const float* __restrict__ wq, const float* __restrict__ wk,
    const float* __restrict__ wv, const float* __restrict__ wc,
    __hip_bfloat16* __restrict__ WT, __hip_bfloat16* __restrict__ wcT)
{
    int z = blockIdx.z;
    const float* W = (z == 0) ? wq : (z == 1) ? wk : (z == 2) ? wv : wc;
    __hip_bfloat16* T = (z < 3) ? (WT + (size_t)z * 1048576) : wcT;
    __shared__ float tile[64][65];
    int k0 = blockIdx.y * 64, n0 = blockIdx.x * 64;
    for (int i = threadIdx.x; i < 4096; i += 256) {
        int r = i >> 6, cc = i & 63;
        tile[r][cc] = W[(size_t)(k0 + r) * 1024 + n0 + cc];
    }
    __syncthreads();
    for (int i = threadIdx.x; i < 4096; i += 256) {
        int nl = i >> 6, kl = i & 63;
        T[(size_t)(n0 + nl) * 1024 + k0 + kl] = __float2bfloat16(tile[kl][nl]);
    }
}

// ---------------- GEMM: C[m][n] = (X[m][:] . WT[n][:] + bias[n]) * scale ----------------
// X: [Z][M][K] bf16 row-major, WT: [Z][N][K] bf16 row-major. M=4096, N=K=1024.
__global__ __launch_bounds__(256) void gemm_bt(
    const __hip_bfloat16* __restrict__ X, const __hip_bfloat16* __restrict__ WT,
    const float* __restrict__ bias, float* __restrict__ Cout,
    long zsX, long zsW, long zsB, long zsC, int applyNorm)
{
    const int K = 1024, N = 1024;
    int z = blockIdx.z;
    const short* Xz = (const short*)(X + (size_t)z * zsX);
    const short* Wz = (const short*)(WT + (size_t)z * zsW);
    const float* bz = bias + (size_t)z * zsB;
    float* Cz = Cout + (size_t)z * zsC;
    float scale = (applyNorm && z < 2) ? 0.35355339059327373f : 1.0f; // 64^-0.25

    __shared__ short As[128 * 32];
    __shared__ short Bs[128 * 32];
    int tid = threadIdx.x;
    int m0 = blockIdx.y * 128;
    int n0 = blockIdx.x * 128;
    int lane = tid & 63;
    int w = tid >> 6;
    int wm = (w >> 1) * 64, wn = (w & 1) * 64;

    f32x4 acc[4][4] = {};

    int srow = tid >> 2;
    int scol = (tid & 3) * 8;
    const short* Ag = Xz + (size_t)(m0 + srow) * K + scol;
    const short* Bg = Wz + (size_t)(n0 + srow) * K + scol;

    int fr = lane & 15, kg = (lane >> 4) * 8;

    for (int kt = 0; kt < K / 32; ++kt) {
        short8 a0 = *(const short8*)(Ag + kt * 32);
        short8 a1 = *(const short8*)(Ag + (size_t)64 * K + kt * 32);
        short8 b0 = *(const short8*)(Bg + kt * 32);
        short8 b1 = *(const short8*)(Bg + (size_t)64 * K + kt * 32);
        __syncthreads();
        *(short8*)&As[srow * 32 + scol] = a0;
        *(short8*)&As[(64 + srow) * 32 + scol] = a1;
        *(short8*)&Bs[srow * 32 + scol] = b0;
        *(short8*)&Bs[(64 + srow) * 32 + scol] = b1;
        __syncthreads();

        short8 af[4], bf[4];
#pragma unroll
        for (int mi = 0; mi < 4; ++mi)
            af[mi] = *(const short8*)&As[(wm + mi * 16 + fr) * 32 + kg];
#pragma unroll
        for (int ni = 0; ni < 4; ++ni)
            bf[ni] = *(const short8*)&Bs[(wn + ni * 16 + fr) * 32 + kg];
#pragma unroll
        for (int mi = 0; mi < 4; ++mi)
#pragma unroll
            for (int ni = 0; ni < 4; ++ni)
                acc[mi][ni] = __builtin_amdgcn_mfma_f32_16x16x32_bf16(af[mi], bf[ni], acc[mi][ni], 0, 0, 0);
    }

    int rg = (lane >> 4) * 4;
#pragma unroll
    for (int mi = 0; mi < 4; ++mi)
#pragma unroll
        for (int ni = 0; ni < 4; ++ni) {
            int gn = n0 + wn + ni * 16 + fr;
            float bval = bz[gn];
#pragma unroll
            for (int i = 0; i < 4; ++i) {
                int gm = m0 + wm + mi * 16 + rg + i;
                Cz[(size_t)gm * N + gn] = (acc[mi][ni][i] + bval) * scale;
            }
        }
}

// ---------------- phi: random-feature map ----------------
// out[bh][s][r] = 0.125 * exp( x . wg[h][:][r] - 0.5*||x||^2 ),  x = X[b][s][h*64 ...]
__global__ __launch_bounds__(256) void k_phi(
    const float* __restrict__ qh, const float* __restrict__ kh,
    const float* __restrict__ wg,
    float* __restrict__ qprime, float* __restrict__ kprime)
{
    int z = blockIdx.z;
    int bh = blockIdx.y;
    int b = bh >> 4, h = bh & 15;
    int s0 = blockIdx.x * 64;
    int tid = threadIdx.x, lane = tid & 63, w = tid >> 6;
    const float* X = (z == 0) ? qh : kh;
    float* O = (z == 0) ? qprime : kprime;

    float wgc[DH];
#pragma unroll
    for (int dd = 0; dd < DH; ++dd)
        wgc[dd] = wg[((size_t)h * DH + dd) * RR + lane];

    __shared__ float xs[64][DH];
    for (int i = tid; i < 64 * DH; i += 256) {
        int rr = i >> 6, dd = i & 63;
        xs[rr][dd] = X[((size_t)b * SS + s0 + rr) * DD + h * DH + dd];
    }
    __syncthreads();

    for (int rr = w; rr < 64; rr += 4) {
        float arg = 0.f, nrm = 0.f;
#pragma unroll
        for (int d4 = 0; d4 < 16; ++d4) {
            float4 xq = *(const float4*)&xs[rr][d4 * 4];
            arg += xq.x * wgc[d4 * 4 + 0] + xq.y * wgc[d4 * 4 + 1]
                 + xq.z * wgc[d4 * 4 + 2] + xq.w * wgc[d4 * 4 + 3];
            nrm += xq.x * xq.x + xq.y * xq.y + xq.z * xq.z + xq.w * xq.w;
        }
        O[((size_t)bh * SS + s0 + rr) * RR + lane] = 0.125f * __expf(arg - 0.5f * nrm);
    }
}

// ---------------- chunk sums: cs[bh][c][r*64+d] = sum_{s in chunk} kp[s][r]*v[s][d] ----------------
__global__ __launch_bounds__(64) void k_chunksum(
    const float* __restrict__ kprime, const float* __restrict__ vh,
    float* __restrict__ cs)
{
    int c = blockIdx.x;
    int bh = blockIdx.y;
    int b = bh >> 4, h = bh & 15;
    int lane = threadIdx.x;
    __shared__ float kp[CH][RR];
    size_t rowbase = (size_t)bh * SS + c * CH;
    for (int i = 0; i < CH; ++i)
        kp[i][lane] = kprime[(rowbase + i) * RR + lane];
    __syncthreads();

    float st[RR];
#pragma unroll
    for (int r = 0; r < RR; ++r) st[r] = 0.f;
    float kpsum = 0.f;
    const float* vptr = vh + ((size_t)b * SS + c * CH) * DD + h * DH + lane;
    for (int s = 0; s < CH; ++s) {
        float vd = vptr[(size_t)s * DD];
        kpsum += kp[s][lane];
#pragma unroll
        for (int rq = 0; rq < RR / 4; ++rq) {
            float4 kq = *(const float4*)&kp[s][rq * 4];
            st[rq * 4 + 0] += kq.x * vd;
            st[rq * 4 + 1] += kq.y * vd;
            st[rq * 4 + 2] += kq.z * vd;
            st[rq * 4 + 3] += kq.w * vd;
        }
    }
    float* out = cs + (size_t)(bh * NCH + c) * CSROW;
#pragma unroll
    for (int r = 0; r < RR; ++r) out[r * 64 + lane] = st[r];
    out[4096 + lane] = kpsum;
}

// ---------------- exclusive scan over chunks (in-place, thread-private columns) ----------------
__global__ __launch_bounds__(256) void k_scan(float* __restrict__ cs)
{
    int t = blockIdx.x * 256 + threadIdx.x;
    if (t >= BH * CSROW) return;
    int bh = t / CSROW;
    int e = t - bh * CSROW;
    float run = 0.f;
    float* p = cs + (size_t)bh * NCH * CSROW + e;
    for (int c = 0; c < NCH; ++c) {
        float v = p[(size_t)c * CSROW];
        p[(size_t)c * CSROW] = run;
        run += v;
    }
}

// ---------------- final: write k_prefix, kv_prefix, attn(bf16) ----------------
__global__ __launch_bounds__(64) void k_scanfinal(
    const float* __restrict__ kprime, const float* __restrict__ qprime,
    const float* __restrict__ vh, const float* __restrict__ cs,
    float* __restrict__ kp_out, float* __restrict__ kv_out,
    __hip_bfloat16* __restrict__ attnb)
{
    int c = blockIdx.x;
    int bh = blockIdx.y;
    int b = bh >> 4, h = bh & 15;
    int lane = threadIdx.x;
    __shared__ float kp[CH][RR];
    __shared__ float qp[CH][RR];
    size_t rowbase = (size_t)bh * SS + c * CH;
    for (int i = 0; i < CH; ++i) {
        kp[i][lane] = kprime[(rowbase + i) * RR + lane];
        qp[i][lane] = qprime[(rowbase + i) * RR + lane];
    }
    __syncthreads();

    const float* off = cs + (size_t)(bh * NCH + c) * CSROW;
    float st[RR];
#pragma unroll
    for (int r = 0; r < RR; ++r) st[r] = off[r * 64 + lane];
    float kps = off[4096 + lane];

    const float* vptr = vh + ((size_t)b * SS + c * CH) * DD + h * DH + lane;
    for (int s = 0; s < CH; ++s) {
        float vd = vptr[(size_t)s * DD];
        kps += kp[s][lane];
        size_t srow = rowbase + s;
        kp_out[srow * RR + lane] = kps;

        float qksum = qp[s][lane] * kps;
#pragma unroll
        for (int m = 1; m < 64; m <<= 1) qksum += __shfl_xor(qksum, m, 64);

        float accd = 0.f;
        float* kvp = kv_out + srow * (size_t)(RR * DH) + lane;
#pragma unroll
        for (int rq = 0; rq < RR / 4; ++rq) {
            float4 kq = *(const float4*)&kp[s][rq * 4];
            float4 qq = *(const float4*)&qp[s][rq * 4];
            st[rq * 4 + 0] += kq.x * vd; accd += qq.x * st[rq * 4 + 0];
            __builtin_nontemporal_store(st[rq * 4 + 0], kvp + (rq * 4 + 0) * 64);
            st[rq * 4 + 1] += kq.y * vd; accd += qq.y * st[rq * 4 + 1];
            __builtin_nontemporal_store(st[rq * 4 + 1], kvp + (rq * 4 + 1) * 64);
            st[rq * 4 + 2] += kq.z * vd; accd += qq.z * st[rq * 4 + 2];
            __builtin_nontemporal_store(st[rq * 4 + 2], kvp + (rq * 4 + 2) * 64);
            st[rq * 4 + 3] += kq.w * vd; accd += qq.w * st[rq * 4 + 3];
            __builtin_nontemporal_store(st[rq * 4 + 3], kvp + (rq * 4 + 3) * 64);
        }
        float attn = accd / (1e-6f + qksum);
        int s_abs = c * CH + s;
        attnb[((size_t)b * SS + s_abs) * DD + h * DH + lane] = __float2bfloat16(attn);
    }
}

extern "C" void kernel_launch(void* const* d_in, const int* in_sizes, int n_in,
                              void* d_out, int out_size, void* d_ws, size_t ws_size,
                              hipStream_t stream) {
    const float* v_in  = (const float*)d_in[0];
    const float* k_in  = (const float*)d_in[1];
    const float* q_in  = (const float*)d_in[2];
    const float* wq_w  = (const float*)d_in[3];
    const float* wq_b  = (const float*)d_in[4];
    const float* wk_w  = (const float*)d_in[5];
    const float* wk_b  = (const float*)d_in[6];
    const float* wv_w  = (const float*)d_in[7];
    const float* wv_b  = (const float*)d_in[8];
    const float* wc_w  = (const float*)d_in[9];
    const float* wc_b  = (const float*)d_in[10];
    const float* wg    = (const float*)d_in[11];

    char* ws = (char*)d_ws;
    __hip_bfloat16* Xb    = (__hip_bfloat16*)(ws + 0);          // [3][4096][1024] bf16
    __hip_bfloat16* WT    = (__hip_bfloat16*)(ws + 25165824);   // [3][1024][1024] bf16
    __hip_bfloat16* wcT   = (__hip_bfloat16*)(ws + 31457280);   // [1024][1024] bf16
    float* biasb          = (float*)(ws + 33554432);            // [3][1024]
    float* qhkv           = (float*)(ws + 33570816);            // [3][4096][1024] f32
    float* qprime         = (float*)(ws + 83902464);            // [32][2048][64] f32
    float* kprime         = (float*)(ws + 100679680);           // [32][2048][64] f32
    float* cs             = (float*)(ws + 117456896);           // [32][64][4160] f32
    __hip_bfloat16* attnb = (__hip_bfloat16*)(ws + 151535616);  // [4096][1024] bf16

    float* kp_out = (float*)d_out;                 // [32][2048][64]
    float* kv_out = kp_out + 4194304;              // [32][2048][64][64]
    float* out_o  = kv_out + 268435456;            // [4096][1024]

    k_prep<<<dim3(4096, 3), 256, 0, stream>>>(q_in, k_in, v_in, wq_b, wk_b, wv_b, Xb, biasb);
    k_wt<<<dim3(16, 16, 4), 256, 0, stream>>>(wq_w, wk_w, wv_w, wc_w, WT, wcT);
    gemm_bt<<<dim3(8, 32, 3), 256, 0, stream>>>(Xb, WT, biasb, qhkv,
                                                4194304L, 1048576L, 1024L, 4194304L, 1);
    k_phi<<<dim3(32, 32, 2), 256, 0, stream>>>(qhkv, qhkv + 4194304, wg, qprime, kprime);
    k_chunksum<<<dim3(NCH, BH), 64, 0, stream>>>(kprime, qhkv + 2 * 4194304, cs);
    k_scan<<<dim3(520), 256, 0, stream>>>(cs);
    k_scanfinal<<<dim3(NCH, BH), 64, 0, stream>>>(kprime, qprime, qhkv + 2 * 4194304, cs,
                                                  kp_out, kv_out, attnb);
    gemm_bt<<<dim3(8, 32, 1), 256, 0, stream>>>(attnb, wcT, wc_b, out_o, 0L, 0L, 0L, 0L, 0);
}